// Round 8
// baseline (105.542 us; speedup 1.0000x reference)
//
#include <hip/hip_runtime.h>
#include <math.h>

// B=16, N=16384, M=256 (derived at runtime).
// d_out: gt_offset (B,3,N) f32 followed by scalar total.
//
// Structure (3 dispatches; kernel boundaries provide cross-XCD visibility —
// round-5 lesson: per-block agent-scope fences/tickets cost ~30-45us on
// 8-XCD gfx950):   memset(82KB ws) -> k1_fused -> k3_final
//
// k1_fused: nearest-contact argmin (contacts in LDS as float4{x,y,z,.5|c|^2},
// broadcast reads, UNROLLED x8 so 8 independent ds_read_b128 issue per wait),
// gt_offset write, smooth-L1 block partial, per-cluster {count,sum(e),sum|e|^2}
// via LDS atomics -> global atomics.  Variance identity:
//   sum||e-mu||^2 = sum||e||^2 - ||sum e||^2 / count
//
// Round-7 lever: VPT 2 -> 1 (grid 512 -> 1024 blocks, 8 -> 16 waves/CU) to
// double latency-hiding for the LDS-broadcast argmin loop. Same VALU work.
//
// Workspace (floats): counts[B*M] | sums[B*M*3] | sq[B*M] | sl1[1]

#define BLK 256
#define UNR 8   // contacts per LDS-read group

__global__ __launch_bounds__(BLK) void k1_fused(
    const float* __restrict__ data,       // (B,3,N)
    const float* __restrict__ cpts,       // (B,M,3)
    const float* __restrict__ pred,       // (B,3,N)
    const int*   __restrict__ tc_arr,     // (B,)
    const int*   __restrict__ label_arr,  // (B,)
    float* __restrict__ gt_out,           // (B,3,N)
    float* __restrict__ counts,           // (B,M)
    float* __restrict__ sums,             // (B,M,3)
    float* __restrict__ sqsum,            // (B,M)
    float* __restrict__ sl1_sum,          // (1,)
    int N, int M, int blocksPerB)
{
    __shared__ float4 c4[256];                                  // x,y,z,.5|c|^2
    __shared__ float lcnt[256], lsx[256], lsy[256], lsz[256], lsq[256];
    __shared__ float redw[BLK / 64];

    const int b     = blockIdx.x / blocksPerB;
    const int chunk = blockIdx.x % blocksPerB;
    const int t     = threadIdx.x;
    const int tc    = tc_arr[b];
    const int lab   = label_arr[b];

    if (t < M) {
        float x = cpts[((size_t)b * M + t) * 3 + 0];
        float y = cpts[((size_t)b * M + t) * 3 + 1];
        float z = cpts[((size_t)b * M + t) * 3 + 2];
        c4[t] = make_float4(x, y, z, 0.5f * (x * x + y * y + z * z));
        lcnt[t] = 0.f; lsx[t] = 0.f; lsy[t] = 0.f; lsz[t] = 0.f; lsq[t] = 0.f;
    }
    __syncthreads();

    const int n = chunk * BLK + t;               // coalesced
    const size_t i = (size_t)b * 3 * N + n;

    const float px = data[i], py = data[i + N], pz = data[i + 2 * (size_t)N];
    const float qx = pred[i], qy = pred[i + N], qz = pred[i + 2 * (size_t)N];

    // argmin over h(c) = 0.5*|c|^2 - p.c   (equiv to argmin d2; |p|^2 const)
    float best = INFINITY; int bi = 0;

    int m = 0;
    for (; m + UNR <= tc; m += UNR) {
        float4 cc[UNR];
        #pragma unroll
        for (int u = 0; u < UNR; ++u) cc[u] = c4[m + u];   // 8 independent ds_read_b128
        #pragma unroll
        for (int u = 0; u < UNR; ++u) {
            float dot = fmaf(cc[u].x, px, fmaf(cc[u].y, py, cc[u].z * pz));
            float h   = cc[u].w - dot;
            bool lt = h < best;
            best = lt ? h       : best;
            bi   = lt ? (m + u) : bi;
        }
    }
    for (; m < tc; ++m) {
        float4 c = c4[m];
        float dot = fmaf(c.x, px, fmaf(c.y, py, c.z * pz));
        float h   = c.w - dot;
        bool lt = h < best;
        best = lt ? h : best;
        bi   = lt ? m : bi;
    }

    float gx = 0.f, gy = 0.f, gz = 0.f;
    if (tc > 0) {
        float4 c = c4[bi];
        gx = c.x - px; gy = c.y - py; gz = c.z - pz;
    }
    gt_out[i]                 = gx;
    gt_out[i + N]             = gy;
    gt_out[i + 2 * (size_t)N] = gz;

    if (tc > 0) {
        float ex = px + qx, ey = py + qy, ez = pz + qz;
        atomicAdd(&lcnt[bi], 1.f);
        atomicAdd(&lsx[bi], ex);
        atomicAdd(&lsy[bi], ey);
        atomicAdd(&lsz[bi], ez);
        atomicAdd(&lsq[bi], ex * ex + ey * ey + ez * ez);
    }

    float s = 0.f;
    if (lab == 1) {
        float d, a;
        d = gx - qx; a = fabsf(d); s += (a < 1.f) ? 0.5f * d * d : (a - 0.5f);
        d = gy - qy; a = fabsf(d); s += (a < 1.f) ? 0.5f * d * d : (a - 0.5f);
        d = gz - qz; a = fabsf(d); s += (a < 1.f) ? 0.5f * d * d : (a - 0.5f);
    }
    #pragma unroll
    for (int o = 32; o > 0; o >>= 1) s += __shfl_down(s, o, 64);
    if ((t & 63) == 0) redw[t >> 6] = s;
    __syncthreads();   // also orders LDS cluster atomics

    if (t == 0) {
        float tot = 0.f;
        #pragma unroll
        for (int w = 0; w < BLK / 64; ++w) tot += redw[w];
        atomicAdd(sl1_sum, tot);
    }
    if (t < M && lcnt[t] > 0.f) {
        const size_t ci = (size_t)b * M + t;
        atomicAdd(&counts[ci], lcnt[t]);
        atomicAdd(&sums[ci * 3 + 0], lsx[t]);
        atomicAdd(&sums[ci * 3 + 1], lsy[t]);
        atomicAdd(&sums[ci * 3 + 2], lsz[t]);
        atomicAdd(&sqsum[ci], lsq[t]);
    }
}

__global__ __launch_bounds__(BLK) void k3_final(
    const int*   __restrict__ tc_arr,
    const int*   __restrict__ label_arr,
    const float* __restrict__ counts,
    const float* __restrict__ sums,
    const float* __restrict__ sqsum,
    const float* __restrict__ sl1_sum,
    float* __restrict__ out_total,
    int B, int M, int N)
{
    __shared__ float red[BLK];
    const int t = threadIdx.x;
    float acc = 0.f;
    for (int i = t; i < B * M; i += BLK) {
        int b = i / M;
        if (tc_arr[b] > 0) {
            float c = counts[i];
            if (c > 0.f) {
                float sx = sums[(size_t)i * 3 + 0];
                float sy = sums[(size_t)i * 3 + 1];
                float sz = sums[(size_t)i * 3 + 2];
                acc += (sqsum[i] - (sx * sx + sy * sy + sz * sz) / c) / c;
            }
        }
    }
    red[t] = acc;
    __syncthreads();
    #pragma unroll
    for (int o = BLK / 2; o > 0; o >>= 1) {
        if (t < o) red[t] += red[t + o];
        __syncthreads();
    }
    if (t == 0) {
        int nvalid = 0, nlab = 0;
        for (int b = 0; b < B; ++b) {
            nvalid += (tc_arr[b] > 0);
            nlab   += (label_arr[b] == 1);
        }
        float var_loss = red[0] / ((float)nvalid + 1e-16f);
        float n_sel    = (float)nlab * 3.f * (float)N;
        float off_loss = (n_sel > 0.f) ? (sl1_sum[0] / n_sel) : 0.f;
        out_total[0] = off_loss * 10.f + var_loss * 2.f;
    }
}

extern "C" void kernel_launch(void* const* d_in, const int* in_sizes, int n_in,
                              void* d_out, int out_size, void* d_ws, size_t ws_size,
                              hipStream_t stream) {
    const float* data  = (const float*)d_in[0];
    const float* cpts  = (const float*)d_in[1];
    const float* pred  = (const float*)d_in[2];
    const int*   tc    = (const int*)d_in[3];
    const int*   label = (const int*)d_in[4];

    const int B = in_sizes[3];
    const int N = in_sizes[0] / (3 * B);
    const int M = in_sizes[1] / (3 * B);

    float* gt_out    = (float*)d_out;
    float* out_total = gt_out + (size_t)B * 3 * N;

    float* counts = (float*)d_ws;                 // B*M
    float* sums   = counts + (size_t)B * M;       // B*M*3
    float* sq     = sums + (size_t)B * M * 3;     // B*M
    float* sl1    = sq + (size_t)B * M;           // 1
    size_t zeroBytes = ((size_t)B * M * 5 + 1) * sizeof(float);

    hipMemsetAsync(d_ws, 0, zeroBytes, stream);

    const int blocksPerB = N / BLK;
    k1_fused<<<dim3(B * blocksPerB), dim3(BLK), 0, stream>>>(
        data, cpts, pred, tc, label, gt_out, counts, sums, sq, sl1,
        N, M, blocksPerB);
    k3_final<<<dim3(1), dim3(BLK), 0, stream>>>(
        tc, label, counts, sums, sq, sl1, out_total, B, M, N);
}

// Round 9
// 102.481 us; speedup vs baseline: 1.0299x; 1.0299x over previous
//
#include <hip/hip_runtime.h>
#include <math.h>

// B=16, N=16384, M=256 (derived at runtime).
// d_out: gt_offset (B,3,N) f32 followed by scalar total.
//
// FINAL (round-7 best config, reverting round-8's VPT=1 experiment):
//   memset(82KB ws) -> k1_fused(VPT=2, UNR=8) -> k3_final
//
// Session lessons encoded here:
//  - r5: per-block agent-scope fences/ticket finalization cost ~30-45us on
//    8-XCD gfx950 (L2 writeback storms); kernel-boundary visibility is free.
//  - r7: x8-unrolled LDS broadcast reads (8 independent ds_read_b128 per
//    lgkmcnt wait) fixed the latency-serialized argmin (136 -> 102.6us).
//  - r8: VPT=1 (2x waves) regressed to 105.5 -> k1 is not occupancy-bound;
//    the remaining ~82us is the harness's two 256MB ws/out re-poison fills.
//  - Variance identity sum||e-mu||^2 = sum||e||^2 - ||sum e||^2/count kills
//    the second data pass entirely.
//
// Workspace (floats): counts[B*M] | sums[B*M*3] | sq[B*M] | sl1[1]

#define BLK 256
#define VPT 2   // points per thread
#define UNR 8   // contacts per LDS-read group

__global__ __launch_bounds__(BLK) void k1_fused(
    const float* __restrict__ data,       // (B,3,N)
    const float* __restrict__ cpts,       // (B,M,3)
    const float* __restrict__ pred,       // (B,3,N)
    const int*   __restrict__ tc_arr,     // (B,)
    const int*   __restrict__ label_arr,  // (B,)
    float* __restrict__ gt_out,           // (B,3,N)
    float* __restrict__ counts,           // (B,M)
    float* __restrict__ sums,             // (B,M,3)
    float* __restrict__ sqsum,            // (B,M)
    float* __restrict__ sl1_sum,          // (1,)
    int N, int M, int blocksPerB)
{
    __shared__ float4 c4[256];                                  // x,y,z,.5|c|^2
    __shared__ float lcnt[256], lsx[256], lsy[256], lsz[256], lsq[256];
    __shared__ float redw[BLK / 64];

    const int b     = blockIdx.x / blocksPerB;
    const int chunk = blockIdx.x % blocksPerB;
    const int t     = threadIdx.x;
    const int tc    = tc_arr[b];
    const int lab   = label_arr[b];

    if (t < M) {
        float x = cpts[((size_t)b * M + t) * 3 + 0];
        float y = cpts[((size_t)b * M + t) * 3 + 1];
        float z = cpts[((size_t)b * M + t) * 3 + 2];
        c4[t] = make_float4(x, y, z, 0.5f * (x * x + y * y + z * z));
        lcnt[t] = 0.f; lsx[t] = 0.f; lsy[t] = 0.f; lsz[t] = 0.f; lsq[t] = 0.f;
    }
    __syncthreads();

    const int n0 = chunk * (BLK * VPT) + t;      // + v*BLK, coalesced
    const size_t base = (size_t)b * 3 * N;

    float px[VPT], py[VPT], pz[VPT], qx[VPT], qy[VPT], qz[VPT];
    #pragma unroll
    for (int v = 0; v < VPT; ++v) {
        const size_t i = base + n0 + v * BLK;
        px[v] = data[i]; py[v] = data[i + N]; pz[v] = data[i + 2 * (size_t)N];
        qx[v] = pred[i]; qy[v] = pred[i + N]; qz[v] = pred[i + 2 * (size_t)N];
    }

    // argmin over h(c) = 0.5*|c|^2 - p.c   (equiv to argmin d2; |p|^2 const)
    float best[VPT]; int bi[VPT];
    #pragma unroll
    for (int v = 0; v < VPT; ++v) { best[v] = INFINITY; bi[v] = 0; }

    int m = 0;
    for (; m + UNR <= tc; m += UNR) {
        float4 cc[UNR];
        #pragma unroll
        for (int u = 0; u < UNR; ++u) cc[u] = c4[m + u];   // 8 independent ds_read_b128
        #pragma unroll
        for (int u = 0; u < UNR; ++u) {
            #pragma unroll
            for (int v = 0; v < VPT; ++v) {
                float dot = fmaf(cc[u].x, px[v], fmaf(cc[u].y, py[v], cc[u].z * pz[v]));
                float h   = cc[u].w - dot;
                bool lt = h < best[v];
                best[v] = lt ? h       : best[v];
                bi[v]   = lt ? (m + u) : bi[v];
            }
        }
    }
    for (; m < tc; ++m) {
        float4 c = c4[m];
        #pragma unroll
        for (int v = 0; v < VPT; ++v) {
            float dot = fmaf(c.x, px[v], fmaf(c.y, py[v], c.z * pz[v]));
            float h   = c.w - dot;
            bool lt = h < best[v];
            best[v] = lt ? h : best[v];
            bi[v]   = lt ? m : bi[v];
        }
    }

    float s = 0.f;
    #pragma unroll
    for (int v = 0; v < VPT; ++v) {
        float gx = 0.f, gy = 0.f, gz = 0.f;
        if (tc > 0) {
            float4 c = c4[bi[v]];
            gx = c.x - px[v]; gy = c.y - py[v]; gz = c.z - pz[v];
        }
        const size_t i = base + n0 + v * BLK;
        gt_out[i]                 = gx;
        gt_out[i + N]             = gy;
        gt_out[i + 2 * (size_t)N] = gz;

        if (tc > 0) {
            float ex = px[v] + qx[v], ey = py[v] + qy[v], ez = pz[v] + qz[v];
            atomicAdd(&lcnt[bi[v]], 1.f);
            atomicAdd(&lsx[bi[v]], ex);
            atomicAdd(&lsy[bi[v]], ey);
            atomicAdd(&lsz[bi[v]], ez);
            atomicAdd(&lsq[bi[v]], ex * ex + ey * ey + ez * ez);
        }
        if (lab == 1) {
            float d, a;
            d = gx - qx[v]; a = fabsf(d); s += (a < 1.f) ? 0.5f * d * d : (a - 0.5f);
            d = gy - qy[v]; a = fabsf(d); s += (a < 1.f) ? 0.5f * d * d : (a - 0.5f);
            d = gz - qz[v]; a = fabsf(d); s += (a < 1.f) ? 0.5f * d * d : (a - 0.5f);
        }
    }

    #pragma unroll
    for (int o = 32; o > 0; o >>= 1) s += __shfl_down(s, o, 64);
    if ((t & 63) == 0) redw[t >> 6] = s;
    __syncthreads();   // also orders LDS cluster atomics

    if (t == 0) {
        float tot = 0.f;
        #pragma unroll
        for (int w = 0; w < BLK / 64; ++w) tot += redw[w];
        atomicAdd(sl1_sum, tot);
    }
    if (t < M && lcnt[t] > 0.f) {
        const size_t ci = (size_t)b * M + t;
        atomicAdd(&counts[ci], lcnt[t]);
        atomicAdd(&sums[ci * 3 + 0], lsx[t]);
        atomicAdd(&sums[ci * 3 + 1], lsy[t]);
        atomicAdd(&sums[ci * 3 + 2], lsz[t]);
        atomicAdd(&sqsum[ci], lsq[t]);
    }
}

__global__ __launch_bounds__(BLK) void k3_final(
    const int*   __restrict__ tc_arr,
    const int*   __restrict__ label_arr,
    const float* __restrict__ counts,
    const float* __restrict__ sums,
    const float* __restrict__ sqsum,
    const float* __restrict__ sl1_sum,
    float* __restrict__ out_total,
    int B, int M, int N)
{
    __shared__ float red[BLK];
    const int t = threadIdx.x;
    float acc = 0.f;
    for (int i = t; i < B * M; i += BLK) {
        int b = i / M;
        if (tc_arr[b] > 0) {
            float c = counts[i];
            if (c > 0.f) {
                float sx = sums[(size_t)i * 3 + 0];
                float sy = sums[(size_t)i * 3 + 1];
                float sz = sums[(size_t)i * 3 + 2];
                acc += (sqsum[i] - (sx * sx + sy * sy + sz * sz) / c) / c;
            }
        }
    }
    red[t] = acc;
    __syncthreads();
    #pragma unroll
    for (int o = BLK / 2; o > 0; o >>= 1) {
        if (t < o) red[t] += red[t + o];
        __syncthreads();
    }
    if (t == 0) {
        int nvalid = 0, nlab = 0;
        for (int b = 0; b < B; ++b) {
            nvalid += (tc_arr[b] > 0);
            nlab   += (label_arr[b] == 1);
        }
        float var_loss = red[0] / ((float)nvalid + 1e-16f);
        float n_sel    = (float)nlab * 3.f * (float)N;
        float off_loss = (n_sel > 0.f) ? (sl1_sum[0] / n_sel) : 0.f;
        out_total[0] = off_loss * 10.f + var_loss * 2.f;
    }
}

extern "C" void kernel_launch(void* const* d_in, const int* in_sizes, int n_in,
                              void* d_out, int out_size, void* d_ws, size_t ws_size,
                              hipStream_t stream) {
    const float* data  = (const float*)d_in[0];
    const float* cpts  = (const float*)d_in[1];
    const float* pred  = (const float*)d_in[2];
    const int*   tc    = (const int*)d_in[3];
    const int*   label = (const int*)d_in[4];

    const int B = in_sizes[3];
    const int N = in_sizes[0] / (3 * B);
    const int M = in_sizes[1] / (3 * B);

    float* gt_out    = (float*)d_out;
    float* out_total = gt_out + (size_t)B * 3 * N;

    float* counts = (float*)d_ws;                 // B*M
    float* sums   = counts + (size_t)B * M;       // B*M*3
    float* sq     = sums + (size_t)B * M * 3;     // B*M
    float* sl1    = sq + (size_t)B * M;           // 1
    size_t zeroBytes = ((size_t)B * M * 5 + 1) * sizeof(float);

    hipMemsetAsync(d_ws, 0, zeroBytes, stream);

    const int blocksPerB = N / (BLK * VPT);
    k1_fused<<<dim3(B * blocksPerB), dim3(BLK), 0, stream>>>(
        data, cpts, pred, tc, label, gt_out, counts, sums, sq, sl1,
        N, M, blocksPerB);
    k3_final<<<dim3(1), dim3(BLK), 0, stream>>>(
        tc, label, counts, sums, sq, sl1, out_total, B, M, N);
}